// Round 5
// baseline (349.733 us; speedup 1.0000x reference)
//
#include <hip/hip_runtime.h>
#include <cstdint>
#include <cstddef>

#define MDIM 4096   // batch
#define NDIM 4096   // out features
#define KDIM 4096   // in features

typedef _Float16 half8  __attribute__((ext_vector_type(8)));
typedef __fp16   cvt2   __attribute__((ext_vector_type(2)));   // cvt_pkrtz return type
typedef float    floatx4 __attribute__((ext_vector_type(4)));

// Hamilton product tables: out_comp = sum_c sign[comp][c] * (x_c @ W_{q[comp][c]}^T)
__device__ __constant__ int   d_qtab[16] = {0,1,2,3,  1,0,3,2,  2,3,0,1,  3,2,1,0};
__device__ __constant__ int   d_negtab[16] = {0,1,1,1,  0,0,0,1,  0,1,0,0,  0,0,1,0};
__device__ __constant__ float d_stab[16] = {1.f,-1.f,-1.f,-1.f,
                                            1.f, 1.f, 1.f,-1.f,
                                            1.f,-1.f, 1.f, 1.f,
                                            1.f, 1.f,-1.f, 1.f};

// ---------------- pre-pass: W fp32 -> fp16 cast, BOTH signs ----------------
// Wh layout: [8][1024][1024] fp16 ; index q = +W_q, index 4+q = -W_q
__global__ void cast_w_kernel(const float* __restrict__ W0, const float* __restrict__ W1,
                              const float* __restrict__ W2, const float* __restrict__ W3,
                              _Float16* __restrict__ Wh) {
    int idx = blockIdx.x * 256 + threadIdx.x;          // 0 .. 512K-1
    int e = idx << 3;                                   // element index, 0..4M-1
    int m = e >> 20;                                    // which matrix
    int off = e & ((1 << 20) - 1);
    const float* Ws[4] = {W0, W1, W2, W3};
    const float* src = Ws[m] + off;
    float4 a = *(const float4*)src;
    float4 b = *(const float4*)(src + 4);
    half8 hp = {(_Float16)a.x, (_Float16)a.y, (_Float16)a.z, (_Float16)a.w,
                (_Float16)b.x, (_Float16)b.y, (_Float16)b.z, (_Float16)b.w};
    half8 hn = -hp;
    *(half8*)(Wh + ((size_t)m << 20) + off)       = hp;
    *(half8*)(Wh + ((size_t)(4 + m) << 20) + off) = hn;
}

// ---------------- MFMA GEMM, A = raw fp32 x via LDS-DMA ----------------
// C[M,N] = x[M,K] * W_big[N,K]^T + bias[N]; signs folded into the +-W copies.
// Block: 256 threads (4 waves), tile 128x128, BK=32, single-buffered LDS.
// A staged as fp32 (16 KB), converted to fp16 at fragment-read time.

__device__ __forceinline__ void gload_lds16h(const _Float16* g, _Float16* l) {
    __builtin_amdgcn_global_load_lds(
        (const __attribute__((address_space(1))) unsigned int*)g,
        (__attribute__((address_space(3))) unsigned int*)l,
        16, 0, 0);
}
__device__ __forceinline__ void gload_lds16f(const float* g, float* l) {
    __builtin_amdgcn_global_load_lds(
        (const __attribute__((address_space(1))) unsigned int*)g,
        (__attribute__((address_space(3))) unsigned int*)l,
        16, 0, 0);
}

__global__ __launch_bounds__(256, 4) void gemm_kernel(
        const float* __restrict__ X,         // [4096,4096] fp32 (raw input)
        const _Float16* __restrict__ Wh,     // [8][1024][1024] fp16 (+- copies)
        const float* __restrict__ b0, const float* __restrict__ b1,
        const float* __restrict__ b2, const float* __restrict__ b3,
        float* __restrict__ C) {
    __shared__ float    As[128 * 32];   // 16 KB fp32, row stride 128B (32 banks)
    __shared__ _Float16 Bs[128 * 32];   // 8 KB fp16, row stride 64B

    const int tid  = threadIdx.x;
    const int lane = tid & 63;
    const int wave = tid >> 6;
    const int wm = (wave & 1) * 64;
    const int wn = (wave >> 1) * 64;

    // L2-friendly swizzle: 8 m-tiles per supergroup, n advances inside
    const int g = blockIdx.x;                 // 0..1023 over 32x32 tiles
    const int group_id = g >> 8;              // 0..3
    const int bm = group_id * 8 + (g & 7);
    const int bn = (g & 255) >> 3;
    const int m0 = bm * 128;
    const int n0 = bn * 128;
    const int comp = n0 >> 10;                // output quaternion component (block-uniform)

    // ---- A staging (fp32 DMA, 4 issues): issue r covers rows r*32..r*32+31
    // thread: row-in-issue = tid>>3, 16B slot s = tid&7; global half-chunk
    // g_a = s ^ (row&7) (row&7 == (tid>>3)&7, issue-independent).
    const int arow = tid >> 3;
    const int ga   = (tid & 7) ^ (arow & 7);
    const float* AgBase = X + (size_t)(m0 + arow) * KDIM + ga * 4;
    float* Awr = As + tid * 4;                // == row*32 + s*4

    // ---- B staging (fp16 DMA, 2 issues): 4 threads/row, 16B chunks,
    // global chunk swizzled by row-pair (matches fragment-read swizzle).
    const int srow = tid >> 2;                // 0..63
    const int q_ld = tid & 3;
    const int swz  = (srow >> 1) & 3;
    const int skc  = (q_ld ^ swz) * 8;        // halves
    const int brow = (n0 & 1023) + srow;
    _Float16* Bsl0 = Bs + tid * 8;
    _Float16* Bsl1 = Bs + 2048 + tid * 8;

    floatx4 acc[4][4];
#pragma unroll
    for (int i = 0; i < 4; i++)
#pragma unroll
        for (int j = 0; j < 4; j++)
            acc[i][j] = (floatx4){0.f, 0.f, 0.f, 0.f};

    const int fr = lane & 15;                 // row (A) / col (B) within 16
    const int qf = lane >> 4;                 // k-chunk 0..3
    const int slot8  = (qf ^ ((fr >> 1) & 3)) * 8;      // B LDS chunk (halves)
    const int sa0 = ((2 * qf)     ^ (fr & 7)) * 4;      // A LDS slots (floats)
    const int sa1 = ((2 * qf + 1) ^ (fr & 7)) * 4;

    for (int c = 0; c < 4; c++) {
        const int t = comp * 4 + c;
        const _Float16* Bg0 = Wh + ((size_t)(d_qtab[t] + (d_negtab[t] << 2)) << 20)
                                 + (size_t)brow * 1024 + skc;
        const float*    Ag  = AgBase + c * 1024;

        for (int kk = 0; kk < 1024; kk += 32) {
            // fire-and-forget staging: 4 A-DMA (fp32) + 2 B-DMA (fp16)
#pragma unroll
            for (int r = 0; r < 4; r++)
                gload_lds16f(Ag + kk + (size_t)r * 32 * KDIM, Awr + r * 1024);
            gload_lds16h(Bg0 + kk, Bsl0);
            gload_lds16h(Bg0 + (size_t)64 * 1024 + kk, Bsl1);
            __syncthreads();              // single drain shared by all waves

            half8 af[4], bf[4];
#pragma unroll
            for (int i = 0; i < 4; i++) {
                const float* arp = As + (wm + i * 16 + fr) * 32;
                floatx4 f0 = *(const floatx4*)(arp + sa0);
                floatx4 f1 = *(const floatx4*)(arp + sa1);
                union { cvt2 c[4]; half8 h; } u;
                u.c[0] = __builtin_amdgcn_cvt_pkrtz(f0.x, f0.y);
                u.c[1] = __builtin_amdgcn_cvt_pkrtz(f0.z, f0.w);
                u.c[2] = __builtin_amdgcn_cvt_pkrtz(f1.x, f1.y);
                u.c[3] = __builtin_amdgcn_cvt_pkrtz(f1.z, f1.w);
                af[i] = u.h;
                bf[i] = *(const half8*)(Bs + (wn + i * 16 + fr) * 32 + slot8);
            }
#pragma unroll
            for (int i = 0; i < 4; i++)
#pragma unroll
                for (int j = 0; j < 4; j++)
                    acc[i][j] = __builtin_amdgcn_mfma_f32_16x16x32_f16(af[i], bf[j], acc[i][j], 0, 0, 0);

            __syncthreads();
        }
    }

    // Epilogue: D[row][col], col = lane&15, row = (lane>>4)*4 + r  [m89 layout]
    const int col   = lane & 15;
    const int rquad = (lane >> 4) * 4;
    const float* bs[4] = {b0, b1, b2, b3};
#pragma unroll
    for (int j = 0; j < 4; j++) {
        const int gn = n0 + wn + j * 16 + col;
        const int o  = gn & 1023;
        float bv = 0.f;
#pragma unroll
        for (int c = 0; c < 4; c++)
            bv += d_stab[comp * 4 + c] * bs[d_qtab[comp * 4 + c]][o];
#pragma unroll
        for (int i = 0; i < 4; i++) {
            const int gmb = m0 + wm + i * 16 + rquad;
#pragma unroll
            for (int r = 0; r < 4; r++)
                C[(size_t)(gmb + r) * NDIM + gn] = acc[i][j][r] + bv;
        }
    }
}

// ---------------- fp32 fallback (only if ws too small) ----------------
__global__ void fallback_kernel(const float* __restrict__ x,
                                const float* __restrict__ W0, const float* __restrict__ W1,
                                const float* __restrict__ W2, const float* __restrict__ W3,
                                const float* __restrict__ b0, const float* __restrict__ b1,
                                const float* __restrict__ b2, const float* __restrict__ b3,
                                float* __restrict__ out) {
    int idx = blockIdx.x * 256 + threadIdx.x;   // 16M outputs
    int m = idx >> 12, n = idx & 4095;
    int comp = n >> 10, o = n & 1023;
    const float* Ws[4] = {W0, W1, W2, W3};
    const float* bs[4] = {b0, b1, b2, b3};
    float acc = 0.f;
    for (int c = 0; c < 4; c++) {
        int t = comp * 4 + c;
        const float* wr = Ws[d_qtab[t]] + (size_t)o * 1024;
        const float* xr = x + (size_t)m * 4096 + c * 1024;
        float s = d_stab[t];
        float dot = 0.f;
        for (int i = 0; i < 1024; i += 4) {
            float4 wv = *(const float4*)(wr + i);
            float4 xv = *(const float4*)(xr + i);
            dot += wv.x * xv.x + wv.y * xv.y + wv.z * xv.z + wv.w * xv.w;
        }
        acc += s * dot + s * bs[d_qtab[t]][o];
    }
    out[idx] = acc;
}

// ---------------- launch ----------------
extern "C" void kernel_launch(void* const* d_in, const int* in_sizes, int n_in,
                              void* d_out, int out_size, void* d_ws, size_t ws_size,
                              hipStream_t stream) {
    const float* x = (const float*)d_in[0];
    const float* W[4];
    const float* b[4];
    int wi = 0, bi = 0;
    for (int i = 1; i < n_in && i < 9; i++) {
        if (in_sizes[i] > 4096) { if (wi < 4) W[wi++] = (const float*)d_in[i]; }
        else                    { if (bi < 4) b[bi++] = (const float*)d_in[i]; }
    }
    float* out = (float*)d_out;

    const size_t wh_elems = (size_t)8 * 1024 * 1024;    // 8M fp16 = 16 MB
    const size_t needed = wh_elems * 2;

    if (ws_size < needed) {
        fallback_kernel<<<(MDIM * NDIM) / 256, 256, 0, stream>>>(
            x, W[0], W[1], W[2], W[3], b[0], b[1], b[2], b[3], out);
        return;
    }

    _Float16* Wh = (_Float16*)d_ws;

    cast_w_kernel<<<(4 * 1024 * 1024) / (256 * 8), 256, 0, stream>>>(W[0], W[1], W[2], W[3], Wh);
    gemm_kernel<<<(MDIM / 128) * (NDIM / 128), 256, 0, stream>>>(
        x, Wh, b[0], b[1], b[2], b[3], out);
}

// Round 6
// 314.656 us; speedup vs baseline: 1.1115x; 1.1115x over previous
//
#include <hip/hip_runtime.h>
#include <cstdint>
#include <cstddef>

#define MDIM 4096   // batch
#define NDIM 4096   // out features
#define KDIM 4096   // in features

typedef _Float16 half8   __attribute__((ext_vector_type(8)));
typedef float    floatx16 __attribute__((ext_vector_type(16)));

// Hamilton product tables: out_comp = sum_c sign[comp][c] * (x_c @ W_{q[comp][c]}^T)
__device__ __constant__ int   d_qtab[16] = {0,1,2,3,  1,0,3,2,  2,3,0,1,  3,2,1,0};
__device__ __constant__ int   d_negtab[16] = {0,1,1,1,  0,0,0,1,  0,1,0,0,  0,0,1,0};
__device__ __constant__ float d_stab[16] = {1.f,-1.f,-1.f,-1.f,
                                            1.f, 1.f, 1.f,-1.f,
                                            1.f,-1.f, 1.f, 1.f,
                                            1.f, 1.f,-1.f, 1.f};

// ---------------- fused pre-pass: cast x -> fp16, cast W -> +-fp16 ----------------
// blocks [0,8192): x cast (8 elems/thread). blocks [8192,10240): W cast, both signs.
// Wh layout: [8][1024][1024] fp16 ; index q = +W_q, index 4+q = -W_q
__global__ void prepass_kernel(const float* __restrict__ x,
                               const float* __restrict__ W0, const float* __restrict__ W1,
                               const float* __restrict__ W2, const float* __restrict__ W3,
                               _Float16* __restrict__ xh, _Float16* __restrict__ Wh) {
    int b = blockIdx.x;
    if (b < 8192) {
        int idx = b * 256 + threadIdx.x;               // 0 .. 2M-1
        const float4* src = (const float4*)x + (size_t)idx * 2;
        float4 a = src[0], v = src[1];
        half8 h = {(_Float16)a.x, (_Float16)a.y, (_Float16)a.z, (_Float16)a.w,
                   (_Float16)v.x, (_Float16)v.y, (_Float16)v.z, (_Float16)v.w};
        ((half8*)xh)[idx] = h;
    } else {
        int idx = (b - 8192) * 256 + threadIdx.x;      // 0 .. 512K-1
        int e = idx << 3;                               // 0 .. 4M-1
        int m = e >> 20;
        int off = e & ((1 << 20) - 1);
        const float* Ws[4] = {W0, W1, W2, W3};
        const float* src = Ws[m] + off;
        float4 a = *(const float4*)src;
        float4 v = *(const float4*)(src + 4);
        half8 hp = {(_Float16)a.x, (_Float16)a.y, (_Float16)a.z, (_Float16)a.w,
                    (_Float16)v.x, (_Float16)v.y, (_Float16)v.z, (_Float16)v.w};
        half8 hn = -hp;
        *(half8*)(Wh + ((size_t)m << 20) + off)       = hp;
        *(half8*)(Wh + ((size_t)(4 + m) << 20) + off) = hn;
    }
}

// ---------------- MFMA GEMM (32x32x16 f16) ----------------
// C[M,N] = xh[M,K] * W_big[N,K]^T + bias[N]; signs folded into +-W copies.
// Block: 256 threads (4 waves), tile 128x128, BK=32, single-buffered LDS.
// Wave tile 64x64 = 2x2 of 32x32 MFMAs; 2 k-steps of 16 per BK=32 iter.

__device__ __forceinline__ void gload_lds16(const _Float16* g, _Float16* l) {
    __builtin_amdgcn_global_load_lds(
        (const __attribute__((address_space(1))) unsigned int*)g,
        (__attribute__((address_space(3))) unsigned int*)l,
        16, 0, 0);
}

__global__ __launch_bounds__(256, 4) void gemm_kernel(
        const _Float16* __restrict__ A,      // [4096,4096] fp16
        const _Float16* __restrict__ Wh,     // [8][1024][1024] fp16 (+- copies)
        const float* __restrict__ b0, const float* __restrict__ b1,
        const float* __restrict__ b2, const float* __restrict__ b3,
        float* __restrict__ C) {
    __shared__ _Float16 As[128 * 32];   // 8 KB, row stride 64 B
    __shared__ _Float16 Bs[128 * 32];   // 8 KB

    const int tid  = threadIdx.x;
    const int lane = tid & 63;
    const int wave = tid >> 6;
    const int wm = (wave & 1) * 64;
    const int wn = (wave >> 1) * 64;

    // L2-friendly swizzle: 8 m-tiles per supergroup, n advances inside
    const int g = blockIdx.x;                 // 0..1023 over 32x32 tiles
    const int group_id = g >> 8;              // 0..3
    const int bm = group_id * 8 + (g & 7);
    const int bn = (g & 255) >> 3;
    const int m0 = bm * 128;
    const int n0 = bn * 128;
    const int comp = n0 >> 10;                // output quaternion component (block-uniform)

    // staging: 4 threads/row, 16B chunks; global chunk swizzled by row-pair
    // (identical to R2's proven zero-conflict pattern)
    const int srow = tid >> 2;                // 0..63
    const int q_ld = tid & 3;
    const int swz  = (srow >> 1) & 3;
    const int skc  = (q_ld ^ swz) * 8;        // halves
    const _Float16* Ag0 = A + (size_t)(m0 + srow) * KDIM + skc;
    const int brow = (n0 & 1023) + srow;
    _Float16* Asl0 = As + tid * 8;
    _Float16* Asl1 = As + 2048 + tid * 8;     // rows 64..127 (same swz: (r+64)>>1 mod 4 unchanged)
    _Float16* Bsl0 = Bs + tid * 8;
    _Float16* Bsl1 = Bs + 2048 + tid * 8;

    floatx16 acc[2][2];
#pragma unroll
    for (int i = 0; i < 2; i++)
#pragma unroll
        for (int j = 0; j < 2; j++)
            acc[i][j] = (floatx16)0.f;

    // fragment geometry (32x32x16): m/n = lane&31, k = (lane>>5)*8 + j
    const int fr  = lane & 31;                // row within 32
    const int kh  = lane >> 5;                // k-half 0/1
    const int rsw = (fr >> 1) & 3;            // row-pair swizzle
    // LDS chunk position for k-step s: (2s + kh) ^ rsw
    const int slot_s0 = (((0) + kh) ^ rsw) * 8;
    const int slot_s1 = (((2) + kh) ^ rsw) * 8;

    for (int c = 0; c < 4; c++) {
        const int t = comp * 4 + c;
        const _Float16* Bg0 = Wh + ((size_t)(d_qtab[t] + (d_negtab[t] << 2)) << 20)
                                 + (size_t)brow * 1024 + skc;
        const _Float16* Ag  = Ag0 + c * 1024;

        for (int kk = 0; kk < 1024; kk += 32) {
            gload_lds16(Ag + kk, Asl0);
            gload_lds16(Ag + (size_t)64 * KDIM + kk, Asl1);
            gload_lds16(Bg0 + kk, Bsl0);
            gload_lds16(Bg0 + (size_t)64 * 1024 + kk, Bsl1);
            __syncthreads();

            half8 af[2][2], bf[2][2];     // [i or j][k-step]
#pragma unroll
            for (int i = 0; i < 2; i++) {
                const _Float16* ar = As + (wm + i * 32 + fr) * 32;
                const _Float16* br = Bs + (wn + i * 32 + fr) * 32;
                af[i][0] = *(const half8*)(ar + slot_s0);
                af[i][1] = *(const half8*)(ar + slot_s1);
                bf[i][0] = *(const half8*)(br + slot_s0);
                bf[i][1] = *(const half8*)(br + slot_s1);
            }
#pragma unroll
            for (int s = 0; s < 2; s++)
#pragma unroll
                for (int i = 0; i < 2; i++)
#pragma unroll
                    for (int j = 0; j < 2; j++)
                        acc[i][j] = __builtin_amdgcn_mfma_f32_32x32x16_f16(
                            af[i][s], bf[j][s], acc[i][j], 0, 0, 0);

            __syncthreads();
        }
    }

    // Epilogue: 32x32 C/D layout: col = lane&31, row = (reg&3) + 8*(reg>>2) + 4*(lane>>5)
    const int col = lane & 31;
    const float* bs[4] = {b0, b1, b2, b3};
#pragma unroll
    for (int j = 0; j < 2; j++) {
        const int gn = n0 + wn + j * 32 + col;
        const int o  = gn & 1023;
        float bv = 0.f;
#pragma unroll
        for (int c = 0; c < 4; c++)
            bv += d_stab[comp * 4 + c] * bs[d_qtab[comp * 4 + c]][o];
#pragma unroll
        for (int i = 0; i < 2; i++) {
            const int gmb = m0 + wm + i * 32 + 4 * kh;
#pragma unroll
            for (int reg = 0; reg < 16; reg++) {
                const int row = (reg & 3) + 8 * (reg >> 2);
                C[(size_t)(gmb + row) * NDIM + gn] = acc[i][j][reg] + bv;
            }
        }
    }
}

// ---------------- fp32 fallback (only if ws too small) ----------------
__global__ void fallback_kernel(const float* __restrict__ x,
                                const float* __restrict__ W0, const float* __restrict__ W1,
                                const float* __restrict__ W2, const float* __restrict__ W3,
                                const float* __restrict__ b0, const float* __restrict__ b1,
                                const float* __restrict__ b2, const float* __restrict__ b3,
                                float* __restrict__ out) {
    int idx = blockIdx.x * 256 + threadIdx.x;   // 16M outputs
    int m = idx >> 12, n = idx & 4095;
    int comp = n >> 10, o = n & 1023;
    const float* Ws[4] = {W0, W1, W2, W3};
    const float* bs[4] = {b0, b1, b2, b3};
    float acc = 0.f;
    for (int c = 0; c < 4; c++) {
        int t = comp * 4 + c;
        const float* wr = Ws[d_qtab[t]] + (size_t)o * 1024;
        const float* xr = x + (size_t)m * 4096 + c * 1024;
        float s = d_stab[t];
        float dot = 0.f;
        for (int i = 0; i < 1024; i += 4) {
            float4 wv = *(const float4*)(wr + i);
            float4 xv = *(const float4*)(xr + i);
            dot += wv.x * xv.x + wv.y * xv.y + wv.z * xv.z + wv.w * xv.w;
        }
        acc += s * dot + s * bs[d_qtab[t]][o];
    }
    out[idx] = acc;
}

// ---------------- launch ----------------
extern "C" void kernel_launch(void* const* d_in, const int* in_sizes, int n_in,
                              void* d_out, int out_size, void* d_ws, size_t ws_size,
                              hipStream_t stream) {
    const float* x = (const float*)d_in[0];
    const float* W[4];
    const float* b[4];
    int wi = 0, bi = 0;
    for (int i = 1; i < n_in && i < 9; i++) {
        if (in_sizes[i] > 4096) { if (wi < 4) W[wi++] = (const float*)d_in[i]; }
        else                    { if (bi < 4) b[bi++] = (const float*)d_in[i]; }
    }
    float* out = (float*)d_out;

    const size_t xh_elems = (size_t)MDIM * KDIM;        // 16M fp16 = 32 MB
    const size_t wh_elems = (size_t)8 * 1024 * 1024;    // 8M fp16 = 16 MB
    const size_t needed = (xh_elems + wh_elems) * 2;

    if (ws_size < needed) {
        fallback_kernel<<<(MDIM * NDIM) / 256, 256, 0, stream>>>(
            x, W[0], W[1], W[2], W[3], b[0], b[1], b[2], b[3], out);
        return;
    }

    _Float16* xh = (_Float16*)d_ws;
    _Float16* Wh = xh + xh_elems;

    prepass_kernel<<<8192 + 2048, 256, 0, stream>>>(x, W[0], W[1], W[2], W[3], xh, Wh);
    gemm_kernel<<<(MDIM / 128) * (NDIM / 128), 256, 0, stream>>>(
        xh, Wh, b[0], b[1], b[2], b[3], out);
}

// Round 7
// 279.302 us; speedup vs baseline: 1.2522x; 1.1266x over previous
//
#include <hip/hip_runtime.h>
#include <cstdint>
#include <cstddef>

#define MDIM 4096   // batch
#define NDIM 4096   // out features
#define KDIM 4096   // in features

typedef _Float16 half8   __attribute__((ext_vector_type(8)));
typedef float    floatx4 __attribute__((ext_vector_type(4)));

// Hamilton product tables: out_comp = sum_c sign[comp][c] * (x_c @ W_{q[comp][c]}^T)
__device__ __constant__ int   d_qtab[16] = {0,1,2,3,  1,0,3,2,  2,3,0,1,  3,2,1,0};
__device__ __constant__ float d_stab[16] = {1.f,-1.f,-1.f,-1.f,
                                            1.f, 1.f, 1.f,-1.f,
                                            1.f,-1.f, 1.f, 1.f,
                                            1.f, 1.f,-1.f, 1.f};

// ---------------- fused pre-pass: cast x -> fp16, cast W -> fp16 ----------------
// blocks [0,8192): x cast (8 elems/thread). blocks [8192,10240): W cast.
// Wh layout: [4][1024][1024] fp16
__global__ void prepass_kernel(const float* __restrict__ x,
                               const float* __restrict__ W0, const float* __restrict__ W1,
                               const float* __restrict__ W2, const float* __restrict__ W3,
                               _Float16* __restrict__ xh, _Float16* __restrict__ Wh) {
    int b = blockIdx.x;
    if (b < 8192) {
        int idx = b * 256 + threadIdx.x;               // 0 .. 2M-1
        const float4* src = (const float4*)x + (size_t)idx * 2;
        float4 a = src[0], v = src[1];
        half8 h = {(_Float16)a.x, (_Float16)a.y, (_Float16)a.z, (_Float16)a.w,
                   (_Float16)v.x, (_Float16)v.y, (_Float16)v.z, (_Float16)v.w};
        ((half8*)xh)[idx] = h;
    } else {
        int idx = (b - 8192) * 256 + threadIdx.x;      // 0 .. 512K-1
        int e = idx << 3;                               // 0 .. 4M-1
        int m = e >> 20;
        int off = e & ((1 << 20) - 1);
        const float* Ws[4] = {W0, W1, W2, W3};
        const float* src = Ws[m] + off;
        float4 a = *(const float4*)src;
        float4 v = *(const float4*)(src + 4);
        half8 h = {(_Float16)a.x, (_Float16)a.y, (_Float16)a.z, (_Float16)a.w,
                   (_Float16)v.x, (_Float16)v.y, (_Float16)v.z, (_Float16)v.w};
        *(half8*)(Wh + ((size_t)m << 20) + off) = h;
    }
}

// ---------------- MFMA GEMM (16x16x32 f16, BK=64) ----------------
// C[M,N] = xh[M,K] * W_big[N,K]^T + bias[N]; sign applied to A fragments.
// Block: 256 threads (4 waves), tile 128x128, BK=64 (2 k-steps of 32 per
// barrier -> 32 MFMA per drain, half the barrier count of BK=32).
// LDS rows = 64 halves = 128 B; swizzle slot = chunk ^ (row&7).

__device__ __forceinline__ void gload_lds16(const _Float16* g, _Float16* l) {
    __builtin_amdgcn_global_load_lds(
        (const __attribute__((address_space(1))) unsigned int*)g,
        (__attribute__((address_space(3))) unsigned int*)l,
        16, 0, 0);
}

__global__ __launch_bounds__(256, 4) void gemm_kernel(
        const _Float16* __restrict__ A,      // [4096,4096] fp16
        const _Float16* __restrict__ Wh,     // [4][1024][1024] fp16
        const float* __restrict__ b0, const float* __restrict__ b1,
        const float* __restrict__ b2, const float* __restrict__ b3,
        float* __restrict__ C) {
    __shared__ _Float16 As[128 * 64];   // 16 KB, row stride 128 B
    __shared__ _Float16 Bs[128 * 64];   // 16 KB

    const int tid  = threadIdx.x;
    const int lane = tid & 63;
    const int wave = tid >> 6;
    const int wm = (wave & 1) * 64;
    const int wn = (wave >> 1) * 64;

    // L2-friendly swizzle: 8 m-tiles per supergroup, n advances inside
    const int g = blockIdx.x;                 // 0..1023 over 32x32 tiles
    const int group_id = g >> 8;              // 0..3
    const int bm = group_id * 8 + (g & 7);
    const int bn = (g & 255) >> 3;
    const int m0 = bm * 128;
    const int n0 = bn * 128;
    const int comp = n0 >> 10;                // output quaternion component (block-uniform)

    // ---- staging: 8 threads/row, 16B chunks. Issue r covers rows r*32..r*32+31.
    // LDS dest forced to tid*8 (row = r*32 + tid>>3, slot = tid&7); global
    // chunk g_ch = (tid&7) ^ ((tid>>3)&7) so that stored slot s holds global
    // chunk s ^ (row&7)  -> fragment reads below are 2-way-free.
    const int lrow = tid >> 3;                // 0..31
    const int gch  = (tid & 7) ^ (lrow & 7);  // 0..7
    const _Float16* Ag0 = A + (size_t)(m0 + lrow) * KDIM + gch * 8;
    const int brow0 = (n0 & 1023) + lrow;

    floatx4 acc[4][4];
#pragma unroll
    for (int i = 0; i < 4; i++)
#pragma unroll
        for (int j = 0; j < 4; j++)
            acc[i][j] = (floatx4){0.f, 0.f, 0.f, 0.f};

    // fragment geometry (16x16x32): m/n = fr = lane&15, k = s*32 + qf*8 + j
    const int fr = lane & 15;
    const int qf = lane >> 4;
    const int fsw = fr & 7;                   // row-based slot swizzle
    // slot for k-step s: (4s + qf) ^ fsw
    const int slot_s0 = (((0) + qf) ^ fsw) * 8;
    const int slot_s1 = (((4) + qf) ^ fsw) * 8;

    for (int c = 0; c < 4; c++) {
        const int t = comp * 4 + c;
        const _Float16* Bg0 = Wh + ((size_t)d_qtab[t] << 20)
                                 + (size_t)brow0 * 1024 + gch * 8;
        const _Float16* Ag  = Ag0 + c * 1024;
        const _Float16 s = (_Float16)d_stab[t];
        half8 sv = {s, s, s, s, s, s, s, s};

        for (int kk = 0; kk < 1024; kk += 64) {
            // fire-and-forget staging: 4 A-DMA + 4 B-DMA per thread
#pragma unroll
            for (int r = 0; r < 4; r++) {
                gload_lds16(Ag + kk + (size_t)r * 32 * KDIM, As + r * 2048 + tid * 8);
                gload_lds16(Bg0 + kk + (size_t)r * 32 * 1024, Bs + r * 2048 + tid * 8);
            }
            __syncthreads();

#pragma unroll
            for (int s2 = 0; s2 < 2; s2++) {
                const int slot = s2 ? slot_s1 : slot_s0;
                half8 af[4], bf[4];
#pragma unroll
                for (int i = 0; i < 4; i++) {
                    af[i] = *(const half8*)(As + (wm + i * 16 + fr) * 64 + slot) * sv;
                    bf[i] = *(const half8*)(Bs + (wn + i * 16 + fr) * 64 + slot);
                }
#pragma unroll
                for (int i = 0; i < 4; i++)
#pragma unroll
                    for (int j = 0; j < 4; j++)
                        acc[i][j] = __builtin_amdgcn_mfma_f32_16x16x32_f16(
                            af[i], bf[j], acc[i][j], 0, 0, 0);
            }

            __syncthreads();
        }
    }

    // Epilogue: D[row][col], col = lane&15, row = (lane>>4)*4 + r  [m89 layout]
    const int col   = lane & 15;
    const int rquad = (lane >> 4) * 4;
    const float* bs[4] = {b0, b1, b2, b3};
#pragma unroll
    for (int j = 0; j < 4; j++) {
        const int gn = n0 + wn + j * 16 + col;
        const int o  = gn & 1023;
        float bv = 0.f;
#pragma unroll
        for (int c = 0; c < 4; c++)
            bv += d_stab[comp * 4 + c] * bs[d_qtab[comp * 4 + c]][o];
#pragma unroll
        for (int i = 0; i < 4; i++) {
            const int gmb = m0 + wm + i * 16 + rquad;
#pragma unroll
            for (int r = 0; r < 4; r++)
                C[(size_t)(gmb + r) * NDIM + gn] = acc[i][j][r] + bv;
        }
    }
}

// ---------------- fp32 fallback (only if ws too small) ----------------
__global__ void fallback_kernel(const float* __restrict__ x,
                                const float* __restrict__ W0, const float* __restrict__ W1,
                                const float* __restrict__ W2, const float* __restrict__ W3,
                                const float* __restrict__ b0, const float* __restrict__ b1,
                                const float* __restrict__ b2, const float* __restrict__ b3,
                                float* __restrict__ out) {
    int idx = blockIdx.x * 256 + threadIdx.x;   // 16M outputs
    int m = idx >> 12, n = idx & 4095;
    int comp = n >> 10, o = n & 1023;
    const float* Ws[4] = {W0, W1, W2, W3};
    const float* bs[4] = {b0, b1, b2, b3};
    float acc = 0.f;
    for (int c = 0; c < 4; c++) {
        int t = comp * 4 + c;
        const float* wr = Ws[d_qtab[t]] + (size_t)o * 1024;
        const float* xr = x + (size_t)m * 4096 + c * 1024;
        float s = d_stab[t];
        float dot = 0.f;
        for (int i = 0; i < 1024; i += 4) {
            float4 wv = *(const float4*)(wr + i);
            float4 xv = *(const float4*)(xr + i);
            dot += wv.x * xv.x + wv.y * xv.y + wv.z * xv.z + wv.w * xv.w;
        }
        acc += s * dot + s * bs[d_qtab[t]][o];
    }
    out[idx] = acc;
}

// ---------------- launch ----------------
extern "C" void kernel_launch(void* const* d_in, const int* in_sizes, int n_in,
                              void* d_out, int out_size, void* d_ws, size_t ws_size,
                              hipStream_t stream) {
    const float* x = (const float*)d_in[0];
    const float* W[4];
    const float* b[4];
    int wi = 0, bi = 0;
    for (int i = 1; i < n_in && i < 9; i++) {
        if (in_sizes[i] > 4096) { if (wi < 4) W[wi++] = (const float*)d_in[i]; }
        else                    { if (bi < 4) b[bi++] = (const float*)d_in[i]; }
    }
    float* out = (float*)d_out;

    const size_t xh_elems = (size_t)MDIM * KDIM;        // 16M fp16 = 32 MB
    const size_t wh_elems = (size_t)4 * 1024 * 1024;    // 4M fp16 = 8 MB
    const size_t needed = (xh_elems + wh_elems) * 2;

    if (ws_size < needed) {
        fallback_kernel<<<(MDIM * NDIM) / 256, 256, 0, stream>>>(
            x, W[0], W[1], W[2], W[3], b[0], b[1], b[2], b[3], out);
        return;
    }

    _Float16* xh = (_Float16*)d_ws;
    _Float16* Wh = xh + xh_elems;

    prepass_kernel<<<8192 + 2048, 256, 0, stream>>>(x, W[0], W[1], W[2], W[3], xh, Wh);
    gemm_kernel<<<(MDIM / 128) * (NDIM / 128), 256, 0, stream>>>(
        xh, Wh, b[0], b[1], b[2], b[3], out);
}

// Round 8
// 263.818 us; speedup vs baseline: 1.3257x; 1.0587x over previous
//
#include <hip/hip_runtime.h>
#include <cstdint>
#include <cstddef>

#define MDIM 4096   // batch
#define NDIM 4096   // out features
#define KDIM 4096   // in features

typedef _Float16 half8   __attribute__((ext_vector_type(8)));
typedef float    floatx4 __attribute__((ext_vector_type(4)));

// Hamilton product tables: out_comp = sum_c sign[comp][c] * (x_c @ W_{q[comp][c]}^T)
__device__ __constant__ int   d_qtab[16] = {0,1,2,3,  1,0,3,2,  2,3,0,1,  3,2,1,0};
__device__ __constant__ float d_stab[16] = {1.f,-1.f,-1.f,-1.f,
                                            1.f, 1.f, 1.f,-1.f,
                                            1.f,-1.f, 1.f, 1.f,
                                            1.f, 1.f,-1.f, 1.f};

// ---------------- fused pre-pass: cast x -> fp16, cast W -> fp16 ----------------
// blocks [0,8192): x cast (8 elems/thread). blocks [8192,10240): W cast.
// Wh layout: [4][1024][1024] fp16
__global__ void prepass_kernel(const float* __restrict__ x,
                               const float* __restrict__ W0, const float* __restrict__ W1,
                               const float* __restrict__ W2, const float* __restrict__ W3,
                               _Float16* __restrict__ xh, _Float16* __restrict__ Wh) {
    int b = blockIdx.x;
    if (b < 8192) {
        int idx = b * 256 + threadIdx.x;               // 0 .. 2M-1
        const float4* src = (const float4*)x + (size_t)idx * 2;
        float4 a = src[0], v = src[1];
        half8 h = {(_Float16)a.x, (_Float16)a.y, (_Float16)a.z, (_Float16)a.w,
                   (_Float16)v.x, (_Float16)v.y, (_Float16)v.z, (_Float16)v.w};
        ((half8*)xh)[idx] = h;
    } else {
        int idx = (b - 8192) * 256 + threadIdx.x;      // 0 .. 512K-1
        int e = idx << 3;                               // 0 .. 4M-1
        int m = e >> 20;
        int off = e & ((1 << 20) - 1);
        const float* Ws[4] = {W0, W1, W2, W3};
        const float* src = Ws[m] + off;
        float4 a = *(const float4*)src;
        float4 v = *(const float4*)(src + 4);
        half8 h = {(_Float16)a.x, (_Float16)a.y, (_Float16)a.z, (_Float16)a.w,
                   (_Float16)v.x, (_Float16)v.y, (_Float16)v.z, (_Float16)v.w};
        *(half8*)(Wh + ((size_t)m << 20) + off) = h;
    }
}

// ---------------- MFMA GEMM (16x16x32 f16, BK=64, 256x128 tile) ----------------
// C[M,N] = xh[M,K] * W_big[N,K]^T + bias[N]; sign applied to B fragments.
// Block: 256 threads (4 waves), tile 256(M) x 128(N), BK=64.
// Wave tile 128x64 = 8x4 MFMA grid: 12 ds_read_b128 per 32 MFMA (0.375/MFMA
// vs 0.5 for 64x64) -- LDS read pipe was the modeled 55-60%-busy limiter.
// LDS rows = 64 halves = 128 B; swizzle slot = chunk ^ (row&7)  (R7-proven).

__device__ __forceinline__ void gload_lds16(const _Float16* g, _Float16* l) {
    __builtin_amdgcn_global_load_lds(
        (const __attribute__((address_space(1))) unsigned int*)g,
        (__attribute__((address_space(3))) unsigned int*)l,
        16, 0, 0);
}

__global__ __launch_bounds__(256, 2) void gemm_kernel(
        const _Float16* __restrict__ A,      // [4096,4096] fp16
        const _Float16* __restrict__ Wh,     // [4][1024][1024] fp16
        const float* __restrict__ b0, const float* __restrict__ b1,
        const float* __restrict__ b2, const float* __restrict__ b3,
        float* __restrict__ C) {
    __shared__ _Float16 As[256 * 64];   // 32 KB, row stride 128 B
    __shared__ _Float16 Bs[128 * 64];   // 16 KB

    const int tid  = threadIdx.x;
    const int lane = tid & 63;
    const int wave = tid >> 6;
    const int wm = (wave & 1) * 128;          // M-half of the 256-row tile
    const int wn = (wave >> 1) * 64;          // N-half of the 128-col tile

    // grid: 16 m-tiles x 32 n-tiles; n-inner so consecutive blocks share A-tile
    const int g = blockIdx.x;                 // 0..511
    const int bm = g >> 5;
    const int bn = g & 31;
    const int m0 = bm * 256;
    const int n0 = bn * 128;
    const int comp = n0 >> 10;                // output quaternion component (block-uniform)

    // ---- staging: 8 threads/row, 16B chunks; issue r covers rows r*32..r*32+31.
    // LDS dest tid*8 (row = r*32 + tid>>3, slot = tid&7); global chunk
    // gch = (tid&7) ^ (lrow&7) => stored slot s holds global chunk s^(row&7).
    const int lrow = tid >> 3;                // 0..31
    const int gch  = (tid & 7) ^ (lrow & 7);  // 0..7
    const _Float16* Ag0 = A + (size_t)(m0 + lrow) * KDIM + gch * 8;
    const int brow0 = (n0 & 1023) + lrow;

    floatx4 acc[8][4];
#pragma unroll
    for (int i = 0; i < 8; i++)
#pragma unroll
        for (int j = 0; j < 4; j++)
            acc[i][j] = (floatx4){0.f, 0.f, 0.f, 0.f};

    // fragment geometry (16x16x32): m/n = fr = lane&15, k = s*32 + qf*8 + j
    const int fr = lane & 15;
    const int qf = lane >> 4;
    const int fsw = fr & 7;                   // row-based slot swizzle
    const int slot_s0 = (((0) + qf) ^ fsw) * 8;
    const int slot_s1 = (((4) + qf) ^ fsw) * 8;

    for (int c = 0; c < 4; c++) {
        const int t = comp * 4 + c;
        const _Float16* Bg0 = Wh + ((size_t)d_qtab[t] << 20)
                                 + (size_t)brow0 * 1024 + gch * 8;
        const _Float16* Ag  = Ag0 + c * 1024;
        const _Float16 s = (_Float16)d_stab[t];
        half8 sv = {s, s, s, s, s, s, s, s};

        for (int kk = 0; kk < 1024; kk += 64) {
            // fire-and-forget staging: 8 A-DMA + 4 B-DMA per thread
#pragma unroll
            for (int r = 0; r < 8; r++)
                gload_lds16(Ag + kk + (size_t)r * 32 * KDIM, As + r * 2048 + tid * 8);
#pragma unroll
            for (int r = 0; r < 4; r++)
                gload_lds16(Bg0 + kk + (size_t)r * 32 * 1024, Bs + r * 2048 + tid * 8);
            __syncthreads();

#pragma unroll
            for (int s2 = 0; s2 < 2; s2++) {
                const int slot = s2 ? slot_s1 : slot_s0;
                half8 af[8], bf[4];
#pragma unroll
                for (int j = 0; j < 4; j++)
                    bf[j] = *(const half8*)(Bs + (wn + j * 16 + fr) * 64 + slot) * sv;
#pragma unroll
                for (int i = 0; i < 8; i++)
                    af[i] = *(const half8*)(As + (wm + i * 16 + fr) * 64 + slot);
#pragma unroll
                for (int i = 0; i < 8; i++)
#pragma unroll
                    for (int j = 0; j < 4; j++)
                        acc[i][j] = __builtin_amdgcn_mfma_f32_16x16x32_f16(
                            af[i], bf[j], acc[i][j], 0, 0, 0);
            }

            __syncthreads();
        }
    }

    // Epilogue: D[row][col], col = lane&15, row = (lane>>4)*4 + r  [m89 layout]
    const int col   = lane & 15;
    const int rquad = (lane >> 4) * 4;
    const float* bs[4] = {b0, b1, b2, b3};
#pragma unroll
    for (int j = 0; j < 4; j++) {
        const int gn = n0 + wn + j * 16 + col;
        const int o  = gn & 1023;
        float bv = 0.f;
#pragma unroll
        for (int c = 0; c < 4; c++)
            bv += d_stab[comp * 4 + c] * bs[d_qtab[comp * 4 + c]][o];
#pragma unroll
        for (int i = 0; i < 8; i++) {
            const int gmb = m0 + wm + i * 16 + rquad;
#pragma unroll
            for (int r = 0; r < 4; r++)
                C[(size_t)(gmb + r) * NDIM + gn] = acc[i][j][r] + bv;
        }
    }
}

// ---------------- fp32 fallback (only if ws too small) ----------------
__global__ void fallback_kernel(const float* __restrict__ x,
                                const float* __restrict__ W0, const float* __restrict__ W1,
                                const float* __restrict__ W2, const float* __restrict__ W3,
                                const float* __restrict__ b0, const float* __restrict__ b1,
                                const float* __restrict__ b2, const float* __restrict__ b3,
                                float* __restrict__ out) {
    int idx = blockIdx.x * 256 + threadIdx.x;   // 16M outputs
    int m = idx >> 12, n = idx & 4095;
    int comp = n >> 10, o = n & 1023;
    const float* Ws[4] = {W0, W1, W2, W3};
    const float* bs[4] = {b0, b1, b2, b3};
    float acc = 0.f;
    for (int c = 0; c < 4; c++) {
        int t = comp * 4 + c;
        const float* wr = Ws[d_qtab[t]] + (size_t)o * 1024;
        const float* xr = x + (size_t)m * 4096 + c * 1024;
        float s = d_stab[t];
        float dot = 0.f;
        for (int i = 0; i < 1024; i += 4) {
            float4 wv = *(const float4*)(wr + i);
            float4 xv = *(const float4*)(xr + i);
            dot += wv.x * xv.x + wv.y * xv.y + wv.z * xv.z + wv.w * xv.w;
        }
        acc += s * dot + s * bs[d_qtab[t]][o];
    }
    out[idx] = acc;
}

// ---------------- launch ----------------
extern "C" void kernel_launch(void* const* d_in, const int* in_sizes, int n_in,
                              void* d_out, int out_size, void* d_ws, size_t ws_size,
                              hipStream_t stream) {
    const float* x = (const float*)d_in[0];
    const float* W[4];
    const float* b[4];
    int wi = 0, bi = 0;
    for (int i = 1; i < n_in && i < 9; i++) {
        if (in_sizes[i] > 4096) { if (wi < 4) W[wi++] = (const float*)d_in[i]; }
        else                    { if (bi < 4) b[bi++] = (const float*)d_in[i]; }
    }
    float* out = (float*)d_out;

    const size_t xh_elems = (size_t)MDIM * KDIM;        // 16M fp16 = 32 MB
    const size_t wh_elems = (size_t)4 * 1024 * 1024;    // 4M fp16 = 8 MB
    const size_t needed = (xh_elems + wh_elems) * 2;

    if (ws_size < needed) {
        fallback_kernel<<<(MDIM * NDIM) / 256, 256, 0, stream>>>(
            x, W[0], W[1], W[2], W[3], b[0], b[1], b[2], b[3], out);
        return;
    }

    _Float16* xh = (_Float16*)d_ws;
    _Float16* Wh = xh + xh_elems;

    prepass_kernel<<<8192 + 2048, 256, 0, stream>>>(x, W[0], W[1], W[2], W[3], xh, Wh);
    gemm_kernel<<<(MDIM / 256) * (NDIM / 128), 256, 0, stream>>>(
        xh, Wh, b[0], b[1], b[2], b[3], out);
}